// Round 1
// baseline (5837.277 us; speedup 1.0000x reference)
//
#include <hip/hip_runtime.h>

#define NUSERS 50000
#define NITEMS 50000
#define NN (NUSERS + NITEMS)
#define KDIM 64
#define NLAYERS 3
#define FEAT 2048
#define NEDGES 2000000
#define BATCH 8192
#define SLOPE 0.2f

// ---------------- init: x = concat(Gu, Gi) ----------------
__global__ __launch_bounds__(256) void init_x_kernel(const float* __restrict__ Gu,
                                                     const float* __restrict__ Gi,
                                                     float* __restrict__ x) {
    long long i = (long long)blockIdx.x * blockDim.x + threadIdx.x;  // float4 index
    const long long totalU = (long long)NUSERS * KDIM / 4;
    const long long total = (long long)NN * KDIM / 4;
    if (i < totalU) {
        ((float4*)x)[i] = ((const float4*)Gu)[i];
    } else if (i < total) {
        ((float4*)x)[i] = ((const float4*)Gi)[i - totalU];
    }
}

// ---------------- scatter: agg[dst] += x[src] * w ----------------
// one quarter-wave (16 threads) per edge; each thread does 4 dims (float4 load + 4 atomics)
__global__ __launch_bounds__(256) void scatter_kernel(const float* __restrict__ x,
                                                      const int* __restrict__ ei,
                                                      const float* __restrict__ ew,
                                                      float* __restrict__ agg) {
    long long tid = (long long)blockIdx.x * blockDim.x + threadIdx.x;
    const long long total = (long long)NEDGES * 16;
    if (tid >= total) return;
    int e = (int)(tid >> 4);
    int q = (int)(tid & 15);
    int src = ei[e];
    int dst = ei[NEDGES + e];
    float w = ew[e];
    float4 v = *(const float4*)(x + (long long)src * KDIM + q * 4);
    float* a = agg + (long long)dst * KDIM + q * 4;
    atomicAdd(a + 0, v.x * w);
    atomicAdd(a + 1, v.y * w);
    atomicAdd(a + 2, v.z * w);
    atomicAdd(a + 3, v.w * w);
}

// ---------------- NGCF layer: h = l2norm(leaky(W1(x+agg)+b1 + W2(x*agg)+b2)) ----------------
// one wave per row; weights transposed into LDS (lane j reads W[k*64+j] -> 2-way bank alias, free)
__global__ __launch_bounds__(256) void layer_kernel(const float* __restrict__ xin,
                                                    const float* __restrict__ agg,
                                                    const float* __restrict__ W1,
                                                    const float* __restrict__ b1,
                                                    const float* __restrict__ W2,
                                                    const float* __restrict__ b2,
                                                    float* __restrict__ xout, int layer) {
    __shared__ float W1t[KDIM * KDIM];
    __shared__ float W2t[KDIM * KDIM];
    __shared__ float b1s[KDIM], b2s[KDIM];
    const float* W1g = W1 + (long long)layer * KDIM * KDIM;
    const float* W2g = W2 + (long long)layer * KDIM * KDIM;
    for (int idx = threadIdx.x; idx < KDIM * KDIM; idx += blockDim.x) {
        int j = idx >> 6, k = idx & 63;
        W1t[k * KDIM + j] = W1g[idx];
        W2t[k * KDIM + j] = W2g[idx];
    }
    if (threadIdx.x < KDIM) {
        b1s[threadIdx.x] = b1[layer * KDIM + threadIdx.x];
        b2s[threadIdx.x] = b2[layer * KDIM + threadIdx.x];
    }
    __syncthreads();
    int lane = threadIdx.x & 63;
    int wid = threadIdx.x >> 6;
    int wavesTotal = gridDim.x * (blockDim.x >> 6);
    int gwave = blockIdx.x * (blockDim.x >> 6) + wid;
    for (int n = gwave; n < NN; n += wavesTotal) {
        float xv = xin[(long long)n * KDIM + lane];
        float av = agg[(long long)n * KDIM + lane];
        float s = xv + av;
        float p = xv * av;
        float h = b1s[lane] + b2s[lane];
#pragma unroll
        for (int k = 0; k < KDIM; ++k) {
            float sk = __shfl(s, k);
            float pk = __shfl(p, k);
            h += sk * W1t[k * KDIM + lane] + pk * W2t[k * KDIM + lane];
        }
        h = h > 0.f ? h : SLOPE * h;
        float sq = h * h;
#pragma unroll
        for (int off = 32; off > 0; off >>= 1) sq += __shfl_xor(sq, off);
        float scale = 1.0f / fmaxf(sqrtf(sq), 1e-12f);
        xout[(long long)n * KDIM + lane] = h * scale;
    }
}

// ---------------- gather batch rows into accB (mean accumulator over layers) ----------------
__global__ __launch_bounds__(256) void gather_acc_kernel(const float* __restrict__ x,
                                                         const int* __restrict__ users,
                                                         const int* __restrict__ items,
                                                         float* __restrict__ accB, int mode) {
    int tid = blockIdx.x * blockDim.x + threadIdx.x;  // over 2*BATCH*KDIM
    if (tid >= 2 * BATCH * KDIM) return;
    int b = tid >> 6, lane = tid & 63;
    int node = (b < BATCH) ? users[b] : (NUSERS + items[b - BATCH]);
    float v = x[(long long)node * KDIM + lane];
    if (mode == 0)
        accB[tid] = v;
    else
        accB[tid] += v;
}

// ---------------- transpose proj_w [64,2048] -> wt [2048,64] ----------------
__global__ __launch_bounds__(256) void transpose_w_kernel(const float* __restrict__ pw,
                                                          float* __restrict__ wt) {
    int tid = blockIdx.x * blockDim.x + threadIdx.x;
    if (tid >= KDIM * FEAT) return;
    int j = tid / FEAT, k = tid % FEAT;
    wt[k * KDIM + j] = pw[tid];
}

// ---------------- projection: projB[b] = l2norm(F[items[b]] @ pw^T + pb) ----------------
// one wave handles 4 batch items; lane = output dim j; wt rows are coalesced, L2-resident
__global__ __launch_bounds__(256) void proj_kernel(const float* __restrict__ F,
                                                   const float* __restrict__ wt,
                                                   const float* __restrict__ pb,
                                                   const int* __restrict__ items,
                                                   float* __restrict__ projB) {
    int lane = threadIdx.x & 63;
    int wid = threadIdx.x >> 6;
    int gwave = blockIdx.x * 4 + wid;
    int i0 = gwave * 4;
    if (i0 >= BATCH) return;
    const float* f0 = F + (long long)items[i0 + 0] * FEAT;
    const float* f1 = F + (long long)items[i0 + 1] * FEAT;
    const float* f2 = F + (long long)items[i0 + 2] * FEAT;
    const float* f3 = F + (long long)items[i0 + 3] * FEAT;
    float c0 = 0.f, c1 = 0.f, c2 = 0.f, c3 = 0.f;
    for (int kk = 0; kk < FEAT; kk += 64) {
        float a0 = f0[kk + lane];
        float a1 = f1[kk + lane];
        float a2 = f2[kk + lane];
        float a3 = f3[kk + lane];
#pragma unroll
        for (int k2 = 0; k2 < 64; ++k2) {
            float w = wt[(kk + k2) * KDIM + lane];
            c0 += __shfl(a0, k2) * w;
            c1 += __shfl(a1, k2) * w;
            c2 += __shfl(a2, k2) * w;
            c3 += __shfl(a3, k2) * w;
        }
    }
    float bias = pb[lane];
    c0 += bias; c1 += bias; c2 += bias; c3 += bias;
    float s0 = c0 * c0, s1 = c1 * c1, s2 = c2 * c2, s3 = c3 * c3;
#pragma unroll
    for (int off = 32; off > 0; off >>= 1) {
        s0 += __shfl_xor(s0, off);
        s1 += __shfl_xor(s1, off);
        s2 += __shfl_xor(s2, off);
        s3 += __shfl_xor(s3, off);
    }
    projB[(long long)(i0 + 0) * KDIM + lane] = c0 * (1.0f / fmaxf(sqrtf(s0), 1e-12f));
    projB[(long long)(i0 + 1) * KDIM + lane] = c1 * (1.0f / fmaxf(sqrtf(s1), 1e-12f));
    projB[(long long)(i0 + 2) * KDIM + lane] = c2 * (1.0f / fmaxf(sqrtf(s2), 1e-12f));
    projB[(long long)(i0 + 3) * KDIM + lane] = c3 * (1.0f / fmaxf(sqrtf(s3), 1e-12f));
}

// ---------------- final: xui = dot(gamma_u, gamma_i) + dot(theta_u, proj_i) ----------------
__global__ __launch_bounds__(256) void final_kernel(const float* __restrict__ accB,
                                                    const float* __restrict__ Tu,
                                                    const float* __restrict__ projB,
                                                    const int* __restrict__ users,
                                                    float* __restrict__ out) {
    int lane = threadIdx.x & 63;
    int wid = threadIdx.x >> 6;
    int b = blockIdx.x * 4 + wid;
    if (b >= BATCH) return;
    float gu = accB[(long long)b * KDIM + lane];
    float gi = accB[(long long)(BATCH + b) * KDIM + lane];
    float tu = Tu[(long long)users[b] * KDIM + lane];
    float pi = projB[(long long)b * KDIM + lane];
    float v = gu * gi * (1.0f / 16.0f) + tu * pi;  // (acc/4)·(acc/4)
#pragma unroll
    for (int off = 32; off > 0; off >>= 1) v += __shfl_xor(v, off);
    if (lane == 0) out[b] = v;
}

extern "C" void kernel_launch(void* const* d_in, const int* in_sizes, int n_in,
                              void* d_out, int out_size, void* d_ws, size_t ws_size,
                              hipStream_t stream) {
    const float* Gu = (const float*)d_in[0];
    const float* Gi = (const float*)d_in[1];
    const float* Tu = (const float*)d_in[2];
    const float* F = (const float*)d_in[3];
    const float* pw = (const float*)d_in[4];
    const float* pb = (const float*)d_in[5];
    const float* W1 = (const float*)d_in[6];
    const float* b1 = (const float*)d_in[7];
    const float* W2 = (const float*)d_in[8];
    const float* b2 = (const float*)d_in[9];
    const float* ew = (const float*)d_in[10];
    const int* ei = (const int*)d_in[11];
    const int* users = (const int*)d_in[12];
    const int* items = (const int*)d_in[13];
    float* out = (float*)d_out;

    float* x = (float*)d_ws;                      // NN*KDIM
    float* agg = x + (size_t)NN * KDIM;           // NN*KDIM
    float* accB = agg + (size_t)NN * KDIM;        // 2*BATCH*KDIM
    float* wt = accB + (size_t)2 * BATCH * KDIM;  // FEAT*KDIM
    float* projB = wt + (size_t)FEAT * KDIM;      // BATCH*KDIM

    // x = concat(Gu, Gi)
    {
        long long total = (long long)NN * KDIM / 4;
        int blocks = (int)((total + 255) / 256);
        init_x_kernel<<<blocks, 256, 0, stream>>>(Gu, Gi, x);
    }
    // accB = x0 rows for batch
    gather_acc_kernel<<<(2 * BATCH * KDIM) / 256, 256, 0, stream>>>(x, users, items, accB, 0);
    // transposed projection weight (independent; used later)
    transpose_w_kernel<<<(KDIM * FEAT) / 256, 256, 0, stream>>>(pw, wt);

    for (int l = 0; l < NLAYERS; ++l) {
        hipMemsetAsync(agg, 0, (size_t)NN * KDIM * sizeof(float), stream);
        {
            long long total = (long long)NEDGES * 16;
            int blocks = (int)(total / 256);
            scatter_kernel<<<blocks, 256, 0, stream>>>(x, ei, ew, agg);
        }
        layer_kernel<<<1024, 256, 0, stream>>>(x, agg, W1, b1, W2, b2, x, l);
        gather_acc_kernel<<<(2 * BATCH * KDIM) / 256, 256, 0, stream>>>(x, users, items, accB, 1);
    }

    proj_kernel<<<BATCH / 16, 256, 0, stream>>>(F, wt, pb, items, projB);
    final_kernel<<<BATCH / 4, 256, 0, stream>>>(accB, Tu, projB, users, out);
}

// Round 2
// 3455.914 us; speedup vs baseline: 1.6891x; 1.6891x over previous
//
#include <hip/hip_runtime.h>

#define NUSERS 50000
#define NITEMS 50000
#define NN (NUSERS + NITEMS)
#define KDIM 64
#define NLAYERS 3
#define FEAT 2048
#define NEDGES 2000000
#define BATCH 8192
#define SLOPE 0.2f

// ---------------- init: x = concat(Gu, Gi) ----------------
__global__ __launch_bounds__(256) void init_x_kernel(const float* __restrict__ Gu,
                                                     const float* __restrict__ Gi,
                                                     float* __restrict__ x) {
    long long i = (long long)blockIdx.x * blockDim.x + threadIdx.x;  // float4 index
    const long long totalU = (long long)NUSERS * KDIM / 4;
    const long long total = (long long)NN * KDIM / 4;
    if (i < totalU) {
        ((float4*)x)[i] = ((const float4*)Gu)[i];
    } else if (i < total) {
        ((float4*)x)[i] = ((const float4*)Gi)[i - totalU];
    }
}

// ---------------- CSR build: histogram of dst ----------------
__global__ __launch_bounds__(256) void hist_kernel(const int* __restrict__ ei,
                                                   int* __restrict__ deg) {
    int e = blockIdx.x * blockDim.x + threadIdx.x;
    if (e >= NEDGES) return;
    atomicAdd(&deg[ei[NEDGES + e]], 1);
}

// ---------------- CSR build: exclusive prefix scan (single block, 1024 thr) ----------------
#define SCAN_CHUNK 98  // 1024*98 = 100352 >= NN
__global__ __launch_bounds__(1024) void scan_kernel(const int* __restrict__ deg,
                                                    int* __restrict__ row_start,
                                                    int* __restrict__ cursor) {
    __shared__ int warp_sums[16];
    int t = threadIdx.x;
    int begin = t * SCAN_CHUNK;
    int end = begin + SCAN_CHUNK;
    if (end > NN) end = NN;
    int local = 0;
    for (int i = begin; i < end; ++i) local += deg[i];
    int lane = t & 63, w = t >> 6;
    int v = local;
#pragma unroll
    for (int off = 1; off < 64; off <<= 1) {
        int u = __shfl_up(v, off);
        if (lane >= off) v += u;
    }
    if (lane == 63) warp_sums[w] = v;
    __syncthreads();
    if (w == 0) {
        int s = (lane < 16) ? warp_sums[lane] : 0;
#pragma unroll
        for (int off = 1; off < 16; off <<= 1) {
            int u = __shfl_up(s, off);
            if (lane >= off) s += u;
        }
        if (lane < 16) warp_sums[lane] = s;
    }
    __syncthreads();
    int base = (w > 0 ? warp_sums[w - 1] : 0) + v - local;  // exclusive prefix for thread
    int run = base;
    for (int i = begin; i < end; ++i) {
        row_start[i] = run;
        cursor[i] = run;
        run += deg[i];
    }
    if (t == 0) row_start[NN] = warp_sums[15];
}

// ---------------- CSR build: fill (src, weight) packed ----------------
__global__ __launch_bounds__(256) void fill_kernel(const int* __restrict__ ei,
                                                   const float* __restrict__ ew,
                                                   int* __restrict__ cursor,
                                                   int2* __restrict__ csr) {
    int e = blockIdx.x * blockDim.x + threadIdx.x;
    if (e >= NEDGES) return;
    int src = ei[e];
    int dst = ei[NEDGES + e];
    int pos = atomicAdd(&cursor[dst], 1);
    csr[pos] = make_int2(src, __float_as_int(ew[e]));
}

// ---------------- aggregate: agg[n] = sum_{e: dst=n} w_e * x[src_e]  (pure gather) ----------------
// 16 lanes per node (float4 per lane), 4 nodes per wave
__global__ __launch_bounds__(256) void agg_kernel(const float* __restrict__ x,
                                                  const int2* __restrict__ csr,
                                                  const int* __restrict__ row_start,
                                                  float* __restrict__ agg) {
    int wid = threadIdx.x >> 6;
    int lane = threadIdx.x & 63;
    int g = lane >> 4;
    int l16 = lane & 15;
    int gwave = blockIdx.x * 4 + wid;
    int n = gwave * 4 + g;
    if (n >= NN) return;
    int beg = row_start[n], end = row_start[n + 1];
    float4 acc = make_float4(0.f, 0.f, 0.f, 0.f);
    const float4* x4 = (const float4*)x;
    for (int j = beg; j < end; ++j) {
        int2 pk = csr[j];  // group-uniform address -> broadcast load
        float w = __int_as_float(pk.y);
        float4 v = x4[(long long)pk.x * 16 + l16];
        acc.x += w * v.x;
        acc.y += w * v.y;
        acc.z += w * v.z;
        acc.w += w * v.w;
    }
    ((float4*)agg)[(long long)n * 16 + l16] = acc;
}

// ---------------- NGCF layer GEMM: h = l2norm(leaky(W1(x+agg)+b1 + W2(x*agg)+b2)) ----------------
// block = 256 threads, 64-row tile, full K=64. 4x4 register tile per thread.
// s/p staged in LDS with XOR swizzle; W1t/W2t staged [k][j].
__global__ __launch_bounds__(256) void gemm_layer_kernel(const float* __restrict__ xin,
                                                         const float* __restrict__ agg,
                                                         const float* __restrict__ W1,
                                                         const float* __restrict__ b1,
                                                         const float* __restrict__ W2,
                                                         const float* __restrict__ b2,
                                                         float* __restrict__ xout, int layer) {
    __shared__ float sW1[KDIM * KDIM];  // [k][j]
    __shared__ float sW2[KDIM * KDIM];
    __shared__ float sS[KDIM * KDIM];  // [r][slot^swz]
    __shared__ float sP[KDIM * KDIM];
    const float* W1g = W1 + (long long)layer * KDIM * KDIM;
    const float* W2g = W2 + (long long)layer * KDIM * KDIM;
    int t = threadIdx.x;
    // stage W transposed
    for (int idx = t; idx < KDIM * KDIM; idx += 256) {
        int j = idx >> 6, k = idx & 63;
        sW1[k * KDIM + j] = W1g[idx];
        sW2[k * KDIM + j] = W2g[idx];
    }
    // stage s, p (swizzled)
    int n0 = blockIdx.x * 64;
    {
        int r = t >> 2;
        int node = n0 + r;
        if (node < NN) {
            const float4* xr = (const float4*)(xin + (long long)node * KDIM);
            const float4* ar = (const float4*)(agg + (long long)node * KDIM);
            int swz = (r >> 2) & 7;
#pragma unroll
            for (int i4 = 0; i4 < 4; ++i4) {
                int slot = (t & 3) + i4 * 4;
                float4 xv = xr[slot];
                float4 av = ar[slot];
                float4 sv = make_float4(xv.x + av.x, xv.y + av.y, xv.z + av.z, xv.w + av.w);
                float4 pv = make_float4(xv.x * av.x, xv.y * av.y, xv.z * av.z, xv.w * av.w);
                int ss = slot ^ swz;
                *(float4*)&sS[r * KDIM + ss * 4] = sv;
                *(float4*)&sP[r * KDIM + ss * 4] = pv;
            }
        }
    }
    __syncthreads();

    int tc = t & 15;
    int tr = t >> 4;
    // bias init
    float4 bsum;
    {
        float4 bb1 = *(const float4*)(b1 + layer * KDIM + tc * 4);
        float4 bb2 = *(const float4*)(b2 + layer * KDIM + tc * 4);
        bsum = make_float4(bb1.x + bb2.x, bb1.y + bb2.y, bb1.z + bb2.z, bb1.w + bb2.w);
    }
    float acc[4][4];
#pragma unroll
    for (int i = 0; i < 4; ++i) {
        acc[i][0] = bsum.x; acc[i][1] = bsum.y; acc[i][2] = bsum.z; acc[i][3] = bsum.w;
    }

#pragma unroll
    for (int kc = 0; kc < 16; ++kc) {
        float4 sv[4], pv[4];
#pragma unroll
        for (int i = 0; i < 4; ++i) {
            int r = tr * 4 + i;
            int ss = kc ^ ((r >> 2) & 7);
            sv[i] = *(const float4*)&sS[r * KDIM + ss * 4];
            pv[i] = *(const float4*)&sP[r * KDIM + ss * 4];
        }
#pragma unroll
        for (int kk = 0; kk < 4; ++kk) {
            int k = kc * 4 + kk;
            float4 w1 = *(const float4*)&sW1[k * KDIM + tc * 4];
            float4 w2 = *(const float4*)&sW2[k * KDIM + tc * 4];
#pragma unroll
            for (int i = 0; i < 4; ++i) {
                float s = kk == 0 ? sv[i].x : kk == 1 ? sv[i].y : kk == 2 ? sv[i].z : sv[i].w;
                float p = kk == 0 ? pv[i].x : kk == 1 ? pv[i].y : kk == 2 ? pv[i].z : pv[i].w;
                acc[i][0] += s * w1.x + p * w2.x;
                acc[i][1] += s * w1.y + p * w2.y;
                acc[i][2] += s * w1.z + p * w2.z;
                acc[i][3] += s * w1.w + p * w2.w;
            }
        }
    }

    // epilogue: leaky relu, row l2norm (reduce across 16 lanes sharing tr), store
#pragma unroll
    for (int i = 0; i < 4; ++i) {
        float sq = 0.f;
#pragma unroll
        for (int j = 0; j < 4; ++j) {
            float h = acc[i][j];
            h = h > 0.f ? h : SLOPE * h;
            acc[i][j] = h;
            sq += h * h;
        }
#pragma unroll
        for (int off = 1; off < 16; off <<= 1) sq += __shfl_xor(sq, off);
        float scale = 1.0f / fmaxf(sqrtf(sq), 1e-12f);
        int node = n0 + tr * 4 + i;
        if (node < NN) {
            float4 o = make_float4(acc[i][0] * scale, acc[i][1] * scale, acc[i][2] * scale,
                                   acc[i][3] * scale);
            *(float4*)(xout + (long long)node * KDIM + tc * 4) = o;
        }
    }
}

// ---------------- gather batch rows into accB (mean accumulator over layers) ----------------
__global__ __launch_bounds__(256) void gather_acc_kernel(const float* __restrict__ x,
                                                         const int* __restrict__ users,
                                                         const int* __restrict__ items,
                                                         float* __restrict__ accB, int mode) {
    int tid = blockIdx.x * blockDim.x + threadIdx.x;  // over 2*BATCH*KDIM
    if (tid >= 2 * BATCH * KDIM) return;
    int b = tid >> 6, lane = tid & 63;
    int node = (b < BATCH) ? users[b] : (NUSERS + items[b - BATCH]);
    float v = x[(long long)node * KDIM + lane];
    if (mode == 0)
        accB[tid] = v;
    else
        accB[tid] += v;
}

// ---------------- transpose proj_w [64,2048] -> wt [2048,64] ----------------
__global__ __launch_bounds__(256) void transpose_w_kernel(const float* __restrict__ pw,
                                                          float* __restrict__ wt) {
    int tid = blockIdx.x * blockDim.x + threadIdx.x;
    if (tid >= KDIM * FEAT) return;
    int j = tid / FEAT, k = tid % FEAT;
    wt[k * KDIM + j] = pw[tid];
}

// ---------------- projection: projB[b] = l2norm(F[items[b]] @ pw^T + pb) ----------------
__global__ __launch_bounds__(256) void proj_kernel(const float* __restrict__ F,
                                                   const float* __restrict__ wt,
                                                   const float* __restrict__ pb,
                                                   const int* __restrict__ items,
                                                   float* __restrict__ projB) {
    int lane = threadIdx.x & 63;
    int wid = threadIdx.x >> 6;
    int gwave = blockIdx.x * 4 + wid;
    int i0 = gwave * 4;
    if (i0 >= BATCH) return;
    const float* f0 = F + (long long)items[i0 + 0] * FEAT;
    const float* f1 = F + (long long)items[i0 + 1] * FEAT;
    const float* f2 = F + (long long)items[i0 + 2] * FEAT;
    const float* f3 = F + (long long)items[i0 + 3] * FEAT;
    float c0 = 0.f, c1 = 0.f, c2 = 0.f, c3 = 0.f;
    for (int kk = 0; kk < FEAT; kk += 64) {
        float a0 = f0[kk + lane];
        float a1 = f1[kk + lane];
        float a2 = f2[kk + lane];
        float a3 = f3[kk + lane];
#pragma unroll
        for (int k2 = 0; k2 < 64; ++k2) {
            float w = wt[(kk + k2) * KDIM + lane];
            c0 += __shfl(a0, k2) * w;
            c1 += __shfl(a1, k2) * w;
            c2 += __shfl(a2, k2) * w;
            c3 += __shfl(a3, k2) * w;
        }
    }
    float bias = pb[lane];
    c0 += bias; c1 += bias; c2 += bias; c3 += bias;
    float s0 = c0 * c0, s1 = c1 * c1, s2 = c2 * c2, s3 = c3 * c3;
#pragma unroll
    for (int off = 32; off > 0; off >>= 1) {
        s0 += __shfl_xor(s0, off);
        s1 += __shfl_xor(s1, off);
        s2 += __shfl_xor(s2, off);
        s3 += __shfl_xor(s3, off);
    }
    projB[(long long)(i0 + 0) * KDIM + lane] = c0 * (1.0f / fmaxf(sqrtf(s0), 1e-12f));
    projB[(long long)(i0 + 1) * KDIM + lane] = c1 * (1.0f / fmaxf(sqrtf(s1), 1e-12f));
    projB[(long long)(i0 + 2) * KDIM + lane] = c2 * (1.0f / fmaxf(sqrtf(s2), 1e-12f));
    projB[(long long)(i0 + 3) * KDIM + lane] = c3 * (1.0f / fmaxf(sqrtf(s3), 1e-12f));
}

// ---------------- final: xui = dot(gamma_u, gamma_i) + dot(theta_u, proj_i) ----------------
__global__ __launch_bounds__(256) void final_kernel(const float* __restrict__ accB,
                                                    const float* __restrict__ Tu,
                                                    const float* __restrict__ projB,
                                                    const int* __restrict__ users,
                                                    float* __restrict__ out) {
    int lane = threadIdx.x & 63;
    int wid = threadIdx.x >> 6;
    int b = blockIdx.x * 4 + wid;
    if (b >= BATCH) return;
    float gu = accB[(long long)b * KDIM + lane];
    float gi = accB[(long long)(BATCH + b) * KDIM + lane];
    float tu = Tu[(long long)users[b] * KDIM + lane];
    float pi = projB[(long long)b * KDIM + lane];
    float v = gu * gi * (1.0f / 16.0f) + tu * pi;  // (acc/4)·(acc/4)
#pragma unroll
    for (int off = 32; off > 0; off >>= 1) v += __shfl_xor(v, off);
    if (lane == 0) out[b] = v;
}

extern "C" void kernel_launch(void* const* d_in, const int* in_sizes, int n_in,
                              void* d_out, int out_size, void* d_ws, size_t ws_size,
                              hipStream_t stream) {
    const float* Gu = (const float*)d_in[0];
    const float* Gi = (const float*)d_in[1];
    const float* Tu = (const float*)d_in[2];
    const float* F = (const float*)d_in[3];
    const float* pw = (const float*)d_in[4];
    const float* pb = (const float*)d_in[5];
    const float* W1 = (const float*)d_in[6];
    const float* b1 = (const float*)d_in[7];
    const float* W2 = (const float*)d_in[8];
    const float* b2 = (const float*)d_in[9];
    const float* ew = (const float*)d_in[10];
    const int* ei = (const int*)d_in[11];
    const int* users = (const int*)d_in[12];
    const int* items = (const int*)d_in[13];
    float* out = (float*)d_out;

    float* xa = (float*)d_ws;                      // NN*KDIM
    float* xb = xa + (size_t)NN * KDIM;            // NN*KDIM
    float* agg = xb + (size_t)NN * KDIM;           // NN*KDIM
    float* accB = agg + (size_t)NN * KDIM;         // 2*BATCH*KDIM
    float* wt = accB + (size_t)2 * BATCH * KDIM;   // FEAT*KDIM
    float* projB = wt + (size_t)FEAT * KDIM;       // BATCH*KDIM
    int* deg = (int*)(projB + (size_t)BATCH * KDIM);  // NN+4 (padded)
    int* row_start = deg + (NN + 4);                  // NN+4
    int* cursor = row_start + (NN + 4);               // NN+4
    int2* csr = (int2*)(cursor + (NN + 4));           // NEDGES int2

    // x = concat(Gu, Gi)
    init_x_kernel<<<(int)(((long long)NN * KDIM / 4 + 255) / 256), 256, 0, stream>>>(Gu, Gi, xa);
    gather_acc_kernel<<<(2 * BATCH * KDIM) / 256, 256, 0, stream>>>(xa, users, items, accB, 0);
    transpose_w_kernel<<<(KDIM * FEAT) / 256, 256, 0, stream>>>(pw, wt);

    // CSR build (once; graph is static across layers)
    hipMemsetAsync(deg, 0, (size_t)(NN + 4) * sizeof(int), stream);
    hist_kernel<<<(NEDGES + 255) / 256, 256, 0, stream>>>(ei, deg);
    scan_kernel<<<1, 1024, 0, stream>>>(deg, row_start, cursor);
    fill_kernel<<<(NEDGES + 255) / 256, 256, 0, stream>>>(ei, ew, cursor, csr);

    float* xc = xa;
    float* xn = xb;
    for (int l = 0; l < NLAYERS; ++l) {
        agg_kernel<<<(NN + 15) / 16, 256, 0, stream>>>(xc, csr, row_start, agg);
        gemm_layer_kernel<<<(NN + 63) / 64, 256, 0, stream>>>(xc, agg, W1, b1, W2, b2, xn, l);
        gather_acc_kernel<<<(2 * BATCH * KDIM) / 256, 256, 0, stream>>>(xn, users, items, accB, 1);
        float* tmp = xc; xc = xn; xn = tmp;
    }

    proj_kernel<<<BATCH / 16, 256, 0, stream>>>(F, wt, pb, items, projB);
    final_kernel<<<BATCH / 4, 256, 0, stream>>>(accB, Tu, projB, users, out);
}

// Round 3
// 1109.091 us; speedup vs baseline: 5.2631x; 3.1160x over previous
//
#include <hip/hip_runtime.h>

#define NUSERS 50000
#define NITEMS 50000
#define NN (NUSERS + NITEMS)
#define KDIM 64
#define NLAYERS 3
#define FEAT 2048
#define NEDGES 2000000
#define BATCH 8192
#define SLOPE 0.2f

// ---------------- init: x = concat(Gu, Gi) ----------------
__global__ __launch_bounds__(256) void init_x_kernel(const float* __restrict__ Gu,
                                                     const float* __restrict__ Gi,
                                                     float* __restrict__ x) {
    long long i = (long long)blockIdx.x * blockDim.x + threadIdx.x;  // float4 index
    const long long totalU = (long long)NUSERS * KDIM / 4;
    const long long total = (long long)NN * KDIM / 4;
    if (i < totalU) {
        ((float4*)x)[i] = ((const float4*)Gu)[i];
    } else if (i < total) {
        ((float4*)x)[i] = ((const float4*)Gi)[i - totalU];
    }
}

// ---------------- CSR build: histogram of dst ----------------
__global__ __launch_bounds__(256) void hist_kernel(const int* __restrict__ ei,
                                                   int* __restrict__ deg) {
    int e = blockIdx.x * blockDim.x + threadIdx.x;
    if (e >= NEDGES) return;
    atomicAdd(&deg[ei[NEDGES + e]], 1);
}

// ---------------- CSR build: exclusive prefix scan (single block, 1024 thr) ----------------
#define SCAN_CHUNK 98  // 1024*98 = 100352 >= NN
__global__ __launch_bounds__(1024) void scan_kernel(const int* __restrict__ deg,
                                                    int* __restrict__ row_start,
                                                    int* __restrict__ cursor) {
    __shared__ int warp_sums[16];
    int t = threadIdx.x;
    int begin = t * SCAN_CHUNK;
    int end = begin + SCAN_CHUNK;
    if (end > NN) end = NN;
    int local = 0;
    for (int i = begin; i < end; ++i) local += deg[i];
    int lane = t & 63, w = t >> 6;
    int v = local;
#pragma unroll
    for (int off = 1; off < 64; off <<= 1) {
        int u = __shfl_up(v, off);
        if (lane >= off) v += u;
    }
    if (lane == 63) warp_sums[w] = v;
    __syncthreads();
    if (w == 0) {
        int s = (lane < 16) ? warp_sums[lane] : 0;
#pragma unroll
        for (int off = 1; off < 16; off <<= 1) {
            int u = __shfl_up(s, off);
            if (lane >= off) s += u;
        }
        if (lane < 16) warp_sums[lane] = s;
    }
    __syncthreads();
    int base = (w > 0 ? warp_sums[w - 1] : 0) + v - local;  // exclusive prefix for thread
    int run = base;
    for (int i = begin; i < end; ++i) {
        row_start[i] = run;
        cursor[i] = run;
        run += deg[i];
    }
    if (t == 0) row_start[NN] = warp_sums[15];
}

// ---------------- CSR build: fill (src, weight) packed ----------------
__global__ __launch_bounds__(256) void fill_kernel(const int* __restrict__ ei,
                                                   const float* __restrict__ ew,
                                                   int* __restrict__ cursor,
                                                   int2* __restrict__ csr) {
    int e = blockIdx.x * blockDim.x + threadIdx.x;
    if (e >= NEDGES) return;
    int src = ei[e];
    int dst = ei[NEDGES + e];
    int pos = atomicAdd(&cursor[dst], 1);
    csr[pos] = make_int2(src, __float_as_int(ew[e]));
}

// ---------------- aggregate: agg[n] = sum_{e: dst=n} w_e * x[src_e]  (pure gather) ----------------
// 16 lanes per node (float4 per lane), 4 nodes per wave
__global__ __launch_bounds__(256) void agg_kernel(const float* __restrict__ x,
                                                  const int2* __restrict__ csr,
                                                  const int* __restrict__ row_start,
                                                  float* __restrict__ agg) {
    int wid = threadIdx.x >> 6;
    int lane = threadIdx.x & 63;
    int g = lane >> 4;
    int l16 = lane & 15;
    int gwave = blockIdx.x * 4 + wid;
    int n = gwave * 4 + g;
    if (n >= NN) return;
    int beg = row_start[n], end = row_start[n + 1];
    float4 acc = make_float4(0.f, 0.f, 0.f, 0.f);
    const float4* x4 = (const float4*)x;
    for (int j = beg; j < end; ++j) {
        int2 pk = csr[j];  // group-uniform address -> broadcast load
        float w = __int_as_float(pk.y);
        float4 v = x4[(long long)pk.x * 16 + l16];
        acc.x += w * v.x;
        acc.y += w * v.y;
        acc.z += w * v.z;
        acc.w += w * v.w;
    }
    ((float4*)agg)[(long long)n * 16 + l16] = acc;
}

// ---------------- NGCF layer GEMM: h = l2norm(leaky(W1(x+agg)+b1 + W2(x*agg)+b2)) ----------------
// block = 256 threads, 64-row tile, full K=64. 4x4 register tile per thread.
// Inner loop restructured for bounded register pressure (no spill):
// per kc: 8 weight float4s in named regs, then per-row 2 LDS reads + 32 FMA.
__global__ __launch_bounds__(256) void gemm_layer_kernel(const float* __restrict__ xin,
                                                         const float* __restrict__ agg,
                                                         const float* __restrict__ W1,
                                                         const float* __restrict__ b1,
                                                         const float* __restrict__ W2,
                                                         const float* __restrict__ b2,
                                                         float* __restrict__ xout, int layer) {
    __shared__ float sW1[KDIM * KDIM];  // [k][j]
    __shared__ float sW2[KDIM * KDIM];
    __shared__ float sS[KDIM * KDIM];  // [r][slot^swz]
    __shared__ float sP[KDIM * KDIM];
    const float* W1g = W1 + (long long)layer * KDIM * KDIM;
    const float* W2g = W2 + (long long)layer * KDIM * KDIM;
    int t = threadIdx.x;
    // stage W transposed
    for (int idx = t; idx < KDIM * KDIM; idx += 256) {
        int j = idx >> 6, k = idx & 63;
        sW1[k * KDIM + j] = W1g[idx];
        sW2[k * KDIM + j] = W2g[idx];
    }
    // stage s, p (swizzled)
    int n0 = blockIdx.x * 64;
    {
        int r = t >> 2;
        int node = n0 + r;
        if (node < NN) {
            const float4* xr = (const float4*)(xin + (long long)node * KDIM);
            const float4* ar = (const float4*)(agg + (long long)node * KDIM);
            int swz = (r >> 2) & 7;
#pragma unroll
            for (int i4 = 0; i4 < 4; ++i4) {
                int slot = (t & 3) + i4 * 4;
                float4 xv = xr[slot];
                float4 av = ar[slot];
                float4 sv = make_float4(xv.x + av.x, xv.y + av.y, xv.z + av.z, xv.w + av.w);
                float4 pv = make_float4(xv.x * av.x, xv.y * av.y, xv.z * av.z, xv.w * av.w);
                int ss = slot ^ swz;
                *(float4*)&sS[r * KDIM + ss * 4] = sv;
                *(float4*)&sP[r * KDIM + ss * 4] = pv;
            }
        }
    }
    __syncthreads();

    int tc = t & 15;
    int tr = t >> 4;
    // bias init
    float4 bsum;
    {
        float4 bb1 = *(const float4*)(b1 + layer * KDIM + tc * 4);
        float4 bb2 = *(const float4*)(b2 + layer * KDIM + tc * 4);
        bsum = make_float4(bb1.x + bb2.x, bb1.y + bb2.y, bb1.z + bb2.z, bb1.w + bb2.w);
    }
    float acc[4][4];
#pragma unroll
    for (int i = 0; i < 4; ++i) {
        acc[i][0] = bsum.x; acc[i][1] = bsum.y; acc[i][2] = bsum.z; acc[i][3] = bsum.w;
    }

#pragma unroll 2
    for (int kc = 0; kc < 16; ++kc) {
        float4 w1a = *(const float4*)&sW1[(kc * 4 + 0) * KDIM + tc * 4];
        float4 w1b = *(const float4*)&sW1[(kc * 4 + 1) * KDIM + tc * 4];
        float4 w1c = *(const float4*)&sW1[(kc * 4 + 2) * KDIM + tc * 4];
        float4 w1d = *(const float4*)&sW1[(kc * 4 + 3) * KDIM + tc * 4];
        float4 w2a = *(const float4*)&sW2[(kc * 4 + 0) * KDIM + tc * 4];
        float4 w2b = *(const float4*)&sW2[(kc * 4 + 1) * KDIM + tc * 4];
        float4 w2c = *(const float4*)&sW2[(kc * 4 + 2) * KDIM + tc * 4];
        float4 w2d = *(const float4*)&sW2[(kc * 4 + 3) * KDIM + tc * 4];
#pragma unroll
        for (int i = 0; i < 4; ++i) {
            int r = tr * 4 + i;
            int ss = kc ^ ((r >> 2) & 7);
            float4 sv = *(const float4*)&sS[r * KDIM + ss * 4];
            float4 pv = *(const float4*)&sP[r * KDIM + ss * 4];
            acc[i][0] += sv.x * w1a.x + pv.x * w2a.x;
            acc[i][1] += sv.x * w1a.y + pv.x * w2a.y;
            acc[i][2] += sv.x * w1a.z + pv.x * w2a.z;
            acc[i][3] += sv.x * w1a.w + pv.x * w2a.w;
            acc[i][0] += sv.y * w1b.x + pv.y * w2b.x;
            acc[i][1] += sv.y * w1b.y + pv.y * w2b.y;
            acc[i][2] += sv.y * w1b.z + pv.y * w2b.z;
            acc[i][3] += sv.y * w1b.w + pv.y * w2b.w;
            acc[i][0] += sv.z * w1c.x + pv.z * w2c.x;
            acc[i][1] += sv.z * w1c.y + pv.z * w2c.y;
            acc[i][2] += sv.z * w1c.z + pv.z * w2c.z;
            acc[i][3] += sv.z * w1c.w + pv.z * w2c.w;
            acc[i][0] += sv.w * w1d.x + pv.w * w2d.x;
            acc[i][1] += sv.w * w1d.y + pv.w * w2d.y;
            acc[i][2] += sv.w * w1d.z + pv.w * w2d.z;
            acc[i][3] += sv.w * w1d.w + pv.w * w2d.w;
        }
    }

    // epilogue: leaky relu, row l2norm (reduce across 16 lanes sharing tr), store
#pragma unroll
    for (int i = 0; i < 4; ++i) {
        float sq = 0.f;
#pragma unroll
        for (int j = 0; j < 4; ++j) {
            float h = acc[i][j];
            h = h > 0.f ? h : SLOPE * h;
            acc[i][j] = h;
            sq += h * h;
        }
#pragma unroll
        for (int off = 1; off < 16; off <<= 1) sq += __shfl_xor(sq, off);
        float scale = 1.0f / fmaxf(sqrtf(sq), 1e-12f);
        int node = n0 + tr * 4 + i;
        if (node < NN) {
            float4 o = make_float4(acc[i][0] * scale, acc[i][1] * scale, acc[i][2] * scale,
                                   acc[i][3] * scale);
            *(float4*)(xout + (long long)node * KDIM + tc * 4) = o;
        }
    }
}

// ---------------- gather batch rows into accB (mean accumulator over layers) ----------------
__global__ __launch_bounds__(256) void gather_acc_kernel(const float* __restrict__ x,
                                                         const int* __restrict__ users,
                                                         const int* __restrict__ items,
                                                         float* __restrict__ accB, int mode) {
    int tid = blockIdx.x * blockDim.x + threadIdx.x;  // over 2*BATCH*KDIM
    if (tid >= 2 * BATCH * KDIM) return;
    int b = tid >> 6, lane = tid & 63;
    int node = (b < BATCH) ? users[b] : (NUSERS + items[b - BATCH]);
    float v = x[(long long)node * KDIM + lane];
    if (mode == 0)
        accB[tid] = v;
    else
        accB[tid] += v;
}

// ---------------- transpose proj_w [64,2048] -> wt [2048,64] ----------------
__global__ __launch_bounds__(256) void transpose_w_kernel(const float* __restrict__ pw,
                                                          float* __restrict__ wt) {
    int tid = blockIdx.x * blockDim.x + threadIdx.x;
    if (tid >= KDIM * FEAT) return;
    int j = tid / FEAT, k = tid % FEAT;
    wt[k * KDIM + j] = pw[tid];
}

// ---------------- projection: projB[b] = l2norm(F[items[b]] @ pw^T + pb) ----------------
__global__ __launch_bounds__(256) void proj_kernel(const float* __restrict__ F,
                                                   const float* __restrict__ wt,
                                                   const float* __restrict__ pb,
                                                   const int* __restrict__ items,
                                                   float* __restrict__ projB) {
    int lane = threadIdx.x & 63;
    int wid = threadIdx.x >> 6;
    int gwave = blockIdx.x * 4 + wid;
    int i0 = gwave * 4;
    if (i0 >= BATCH) return;
    const float* f0 = F + (long long)items[i0 + 0] * FEAT;
    const float* f1 = F + (long long)items[i0 + 1] * FEAT;
    const float* f2 = F + (long long)items[i0 + 2] * FEAT;
    const float* f3 = F + (long long)items[i0 + 3] * FEAT;
    float c0 = 0.f, c1 = 0.f, c2 = 0.f, c3 = 0.f;
    for (int kk = 0; kk < FEAT; kk += 64) {
        float a0 = f0[kk + lane];
        float a1 = f1[kk + lane];
        float a2 = f2[kk + lane];
        float a3 = f3[kk + lane];
#pragma unroll
        for (int k2 = 0; k2 < 64; ++k2) {
            float w = wt[(kk + k2) * KDIM + lane];
            c0 += __shfl(a0, k2) * w;
            c1 += __shfl(a1, k2) * w;
            c2 += __shfl(a2, k2) * w;
            c3 += __shfl(a3, k2) * w;
        }
    }
    float bias = pb[lane];
    c0 += bias; c1 += bias; c2 += bias; c3 += bias;
    float s0 = c0 * c0, s1 = c1 * c1, s2 = c2 * c2, s3 = c3 * c3;
#pragma unroll
    for (int off = 32; off > 0; off >>= 1) {
        s0 += __shfl_xor(s0, off);
        s1 += __shfl_xor(s1, off);
        s2 += __shfl_xor(s2, off);
        s3 += __shfl_xor(s3, off);
    }
    projB[(long long)(i0 + 0) * KDIM + lane] = c0 * (1.0f / fmaxf(sqrtf(s0), 1e-12f));
    projB[(long long)(i0 + 1) * KDIM + lane] = c1 * (1.0f / fmaxf(sqrtf(s1), 1e-12f));
    projB[(long long)(i0 + 2) * KDIM + lane] = c2 * (1.0f / fmaxf(sqrtf(s2), 1e-12f));
    projB[(long long)(i0 + 3) * KDIM + lane] = c3 * (1.0f / fmaxf(sqrtf(s3), 1e-12f));
}

// ---------------- final: xui = dot(gamma_u, gamma_i) + dot(theta_u, proj_i) ----------------
__global__ __launch_bounds__(256) void final_kernel(const float* __restrict__ accB,
                                                    const float* __restrict__ Tu,
                                                    const float* __restrict__ projB,
                                                    const int* __restrict__ users,
                                                    float* __restrict__ out) {
    int lane = threadIdx.x & 63;
    int wid = threadIdx.x >> 6;
    int b = blockIdx.x * 4 + wid;
    if (b >= BATCH) return;
    float gu = accB[(long long)b * KDIM + lane];
    float gi = accB[(long long)(BATCH + b) * KDIM + lane];
    float tu = Tu[(long long)users[b] * KDIM + lane];
    float pi = projB[(long long)b * KDIM + lane];
    float v = gu * gi * (1.0f / 16.0f) + tu * pi;  // (acc/4)·(acc/4)
#pragma unroll
    for (int off = 32; off > 0; off >>= 1) v += __shfl_xor(v, off);
    if (lane == 0) out[b] = v;
}

extern "C" void kernel_launch(void* const* d_in, const int* in_sizes, int n_in,
                              void* d_out, int out_size, void* d_ws, size_t ws_size,
                              hipStream_t stream) {
    const float* Gu = (const float*)d_in[0];
    const float* Gi = (const float*)d_in[1];
    const float* Tu = (const float*)d_in[2];
    const float* F = (const float*)d_in[3];
    const float* pw = (const float*)d_in[4];
    const float* pb = (const float*)d_in[5];
    const float* W1 = (const float*)d_in[6];
    const float* b1 = (const float*)d_in[7];
    const float* W2 = (const float*)d_in[8];
    const float* b2 = (const float*)d_in[9];
    const float* ew = (const float*)d_in[10];
    const int* ei = (const int*)d_in[11];
    const int* users = (const int*)d_in[12];
    const int* items = (const int*)d_in[13];
    float* out = (float*)d_out;

    float* xa = (float*)d_ws;                      // NN*KDIM
    float* xb = xa + (size_t)NN * KDIM;            // NN*KDIM
    float* agg = xb + (size_t)NN * KDIM;           // NN*KDIM
    float* accB = agg + (size_t)NN * KDIM;         // 2*BATCH*KDIM
    float* wt = accB + (size_t)2 * BATCH * KDIM;   // FEAT*KDIM
    float* projB = wt + (size_t)FEAT * KDIM;       // BATCH*KDIM
    int* deg = (int*)(projB + (size_t)BATCH * KDIM);  // NN+4 (padded)
    int* row_start = deg + (NN + 4);                  // NN+4
    int* cursor = row_start + (NN + 4);               // NN+4
    int2* csr = (int2*)(cursor + (NN + 4));           // NEDGES int2

    // x = concat(Gu, Gi)
    init_x_kernel<<<(int)(((long long)NN * KDIM / 4 + 255) / 256), 256, 0, stream>>>(Gu, Gi, xa);
    gather_acc_kernel<<<(2 * BATCH * KDIM) / 256, 256, 0, stream>>>(xa, users, items, accB, 0);
    transpose_w_kernel<<<(KDIM * FEAT) / 256, 256, 0, stream>>>(pw, wt);

    // CSR build (once; graph is static across layers)
    hipMemsetAsync(deg, 0, (size_t)(NN + 4) * sizeof(int), stream);
    hist_kernel<<<(NEDGES + 255) / 256, 256, 0, stream>>>(ei, deg);
    scan_kernel<<<1, 1024, 0, stream>>>(deg, row_start, cursor);
    fill_kernel<<<(NEDGES + 255) / 256, 256, 0, stream>>>(ei, ew, cursor, csr);

    float* xc = xa;
    float* xn = xb;
    for (int l = 0; l < NLAYERS; ++l) {
        agg_kernel<<<(NN + 15) / 16, 256, 0, stream>>>(xc, csr, row_start, agg);
        gemm_layer_kernel<<<(NN + 63) / 64, 256, 0, stream>>>(xc, agg, W1, b1, W2, b2, xn, l);
        gather_acc_kernel<<<(2 * BATCH * KDIM) / 256, 256, 0, stream>>>(xn, users, items, accB, 1);
        float* tmp = xc; xc = xn; xn = tmp;
    }

    proj_kernel<<<BATCH / 16, 256, 0, stream>>>(F, wt, pb, items, projB);
    final_kernel<<<BATCH / 4, 256, 0, stream>>>(accB, Tu, projB, users, out);
}

// Round 4
// 850.481 us; speedup vs baseline: 6.8635x; 1.3041x over previous
//
#include <hip/hip_runtime.h>

#define NUSERS 50000
#define NITEMS 50000
#define NN (NUSERS + NITEMS)
#define KDIM 64
#define NLAYERS 3
#define FEAT 2048
#define NEDGES 2000000
#define BATCH 8192
#define SLOPE 0.2f

#define SCAN_TILE 1024
#define SCAN_BLOCKS ((NN + SCAN_TILE - 1) / SCAN_TILE)  // 98
#define DEG_PAD (NN + 1024)

// round-to-nearest-even f32 -> bf16
__device__ __forceinline__ unsigned short f2bf(float f) {
    unsigned int u = __float_as_uint(f);
    unsigned int r = (u + 0x7fffu + ((u >> 16) & 1u)) >> 16;
    return (unsigned short)r;
}

// ---------------- init: x = concat(Gu, Gi); xh = bf16(x) ----------------
__global__ __launch_bounds__(256) void init_x_kernel(const float* __restrict__ Gu,
                                                     const float* __restrict__ Gi,
                                                     float* __restrict__ x,
                                                     unsigned short* __restrict__ xh) {
    long long i = (long long)blockIdx.x * blockDim.x + threadIdx.x;  // float4 index
    const long long totalU = (long long)NUSERS * KDIM / 4;
    const long long total = (long long)NN * KDIM / 4;
    if (i >= total) return;
    float4 v = (i < totalU) ? ((const float4*)Gu)[i] : ((const float4*)Gi)[i - totalU];
    ((float4*)x)[i] = v;
    ushort4 h;
    h.x = f2bf(v.x); h.y = f2bf(v.y); h.z = f2bf(v.z); h.w = f2bf(v.w);
    ((ushort4*)xh)[i] = h;
}

// ---------------- CSR build: histogram of dst ----------------
__global__ __launch_bounds__(256) void hist_kernel(const int* __restrict__ ei,
                                                   int* __restrict__ deg) {
    int e = blockIdx.x * blockDim.x + threadIdx.x;
    if (e >= NEDGES) return;
    atomicAdd(&deg[ei[NEDGES + e]], 1);
}

// ---------------- scan phase 1: per-block (1024-elem tile) sums, coalesced ----------------
__global__ __launch_bounds__(256) void scan_part_kernel(const int* __restrict__ deg,
                                                        int* __restrict__ bsum) {
    int b = blockIdx.x, t = threadIdx.x;
    int base = b * SCAN_TILE + t * 4;
    int4 v = *(const int4*)(deg + base);  // deg padded+zeroed to DEG_PAD
    int s = v.x + v.y + v.z + v.w;
    int lane = t & 63, w = t >> 6;
#pragma unroll
    for (int off = 1; off < 64; off <<= 1) s += __shfl_xor(s, off);
    __shared__ int ws[4];
    if (lane == 0) ws[w] = s;
    __syncthreads();
    if (t == 0) bsum[b] = ws[0] + ws[1] + ws[2] + ws[3];
}

// ---------------- scan phase 2: exclusive scan of 98 block sums ----------------
__global__ __launch_bounds__(128) void scan_tops_kernel(const int* __restrict__ bsum,
                                                        int* __restrict__ boff) {
    int t = threadIdx.x;
    int v = (t < SCAN_BLOCKS) ? bsum[t] : 0;
    int lane = t & 63, w = t >> 6;
    int inc = v;
#pragma unroll
    for (int off = 1; off < 64; off <<= 1) {
        int u = __shfl_up(inc, off);
        if (lane >= off) inc += u;
    }
    __shared__ int w0tot;
    if (w == 0 && lane == 63) w0tot = inc;
    __syncthreads();
    if (w == 1) inc += w0tot;
    if (t < SCAN_BLOCKS) boff[t] = inc - v;
}

// ---------------- scan phase 3: finalize row_start / cursor, coalesced ----------------
__global__ __launch_bounds__(256) void scan_final_kernel(const int* __restrict__ deg,
                                                         const int* __restrict__ boff,
                                                         int* __restrict__ row_start,
                                                         int* __restrict__ cursor) {
    int b = blockIdx.x, t = threadIdx.x;
    int base = b * SCAN_TILE + t * 4;
    int4 v = *(const int4*)(deg + base);
    int tsum = v.x + v.y + v.z + v.w;
    int lane = t & 63, w = t >> 6;
    int inc = tsum;
#pragma unroll
    for (int off = 1; off < 64; off <<= 1) {
        int u = __shfl_up(inc, off);
        if (lane >= off) inc += u;
    }
    __shared__ int wtot[4];
    if (lane == 63) wtot[w] = inc;
    __syncthreads();
    int woff = 0;
    if (w > 0) woff += wtot[0];
    if (w > 1) woff += wtot[1];
    if (w > 2) woff += wtot[2];
    int excl = boff[b] + woff + inc - tsum;
    int4 p;
    p.x = excl;
    p.y = p.x + v.x;
    p.z = p.y + v.y;
    p.w = p.z + v.z;
    *(int4*)(row_start + base) = p;  // padded region: writes prefix==total, incl row_start[NN]
    *(int4*)(cursor + base) = p;
}

// ---------------- CSR build: fill (src, weight) packed ----------------
__global__ __launch_bounds__(256) void fill_kernel(const int* __restrict__ ei,
                                                   const float* __restrict__ ew,
                                                   int* __restrict__ cursor,
                                                   int2* __restrict__ csr) {
    int e = blockIdx.x * blockDim.x + threadIdx.x;
    if (e >= NEDGES) return;
    int src = ei[e];
    int dst = ei[NEDGES + e];
    int pos = atomicAdd(&cursor[dst], 1);
    csr[pos] = make_int2(src, __float_as_int(ew[e]));
}

// ---------------- aggregate: agg[n] = sum_{e: dst=n} w_e * x[src_e] (bf16 gather) ----------------
// 16 lanes per node (4 bf16 dims per lane), 4 nodes per wave
__global__ __launch_bounds__(256) void agg_kernel(const unsigned short* __restrict__ xh,
                                                  const int2* __restrict__ csr,
                                                  const int* __restrict__ row_start,
                                                  float* __restrict__ agg) {
    int wid = threadIdx.x >> 6;
    int lane = threadIdx.x & 63;
    int g = lane >> 4;
    int l16 = lane & 15;
    int gwave = blockIdx.x * 4 + wid;
    int n = gwave * 4 + g;
    if (n >= NN) return;
    int beg = row_start[n], end = row_start[n + 1];
    float4 acc = make_float4(0.f, 0.f, 0.f, 0.f);
    const uint2* x2 = (const uint2*)xh;
    for (int j = beg; j < end; ++j) {
        int2 pk = csr[j];  // group-uniform address -> broadcast load
        float w = __int_as_float(pk.y);
        uint2 u = x2[(long long)pk.x * 16 + l16];
        acc.x += w * __uint_as_float(u.x << 16);
        acc.y += w * __uint_as_float(u.x & 0xFFFF0000u);
        acc.z += w * __uint_as_float(u.y << 16);
        acc.w += w * __uint_as_float(u.y & 0xFFFF0000u);
    }
    ((float4*)agg)[(long long)n * 16 + l16] = acc;
}

// ---------------- NGCF layer GEMM: h = l2norm(leaky(W1(x+agg)+b1 + W2(x*agg)+b2)) ----------------
__global__ __launch_bounds__(256) void gemm_layer_kernel(const float* __restrict__ xin,
                                                         const float* __restrict__ agg,
                                                         const float* __restrict__ W1,
                                                         const float* __restrict__ b1,
                                                         const float* __restrict__ W2,
                                                         const float* __restrict__ b2,
                                                         float* __restrict__ xout,
                                                         unsigned short* __restrict__ xh,
                                                         int layer) {
    __shared__ float sW1[KDIM * KDIM];  // [k][j]
    __shared__ float sW2[KDIM * KDIM];
    __shared__ float sS[KDIM * KDIM];  // [r][slot^swz]
    __shared__ float sP[KDIM * KDIM];
    const float* W1g = W1 + (long long)layer * KDIM * KDIM;
    const float* W2g = W2 + (long long)layer * KDIM * KDIM;
    int t = threadIdx.x;
    for (int idx = t; idx < KDIM * KDIM; idx += 256) {
        int j = idx >> 6, k = idx & 63;
        sW1[k * KDIM + j] = W1g[idx];
        sW2[k * KDIM + j] = W2g[idx];
    }
    int n0 = blockIdx.x * 64;
    {
        int r = t >> 2;
        int node = n0 + r;
        if (node < NN) {
            const float4* xr = (const float4*)(xin + (long long)node * KDIM);
            const float4* ar = (const float4*)(agg + (long long)node * KDIM);
            int swz = (r >> 2) & 7;
#pragma unroll
            for (int i4 = 0; i4 < 4; ++i4) {
                int slot = (t & 3) + i4 * 4;
                float4 xv = xr[slot];
                float4 av = ar[slot];
                float4 sv = make_float4(xv.x + av.x, xv.y + av.y, xv.z + av.z, xv.w + av.w);
                float4 pv = make_float4(xv.x * av.x, xv.y * av.y, xv.z * av.z, xv.w * av.w);
                int ss = slot ^ swz;
                *(float4*)&sS[r * KDIM + ss * 4] = sv;
                *(float4*)&sP[r * KDIM + ss * 4] = pv;
            }
        }
    }
    __syncthreads();

    int tc = t & 15;
    int tr = t >> 4;
    float4 bsum;
    {
        float4 bb1 = *(const float4*)(b1 + layer * KDIM + tc * 4);
        float4 bb2 = *(const float4*)(b2 + layer * KDIM + tc * 4);
        bsum = make_float4(bb1.x + bb2.x, bb1.y + bb2.y, bb1.z + bb2.z, bb1.w + bb2.w);
    }
    float acc[4][4];
#pragma unroll
    for (int i = 0; i < 4; ++i) {
        acc[i][0] = bsum.x; acc[i][1] = bsum.y; acc[i][2] = bsum.z; acc[i][3] = bsum.w;
    }

#pragma unroll 2
    for (int kc = 0; kc < 16; ++kc) {
        float4 w1a = *(const float4*)&sW1[(kc * 4 + 0) * KDIM + tc * 4];
        float4 w1b = *(const float4*)&sW1[(kc * 4 + 1) * KDIM + tc * 4];
        float4 w1c = *(const float4*)&sW1[(kc * 4 + 2) * KDIM + tc * 4];
        float4 w1d = *(const float4*)&sW1[(kc * 4 + 3) * KDIM + tc * 4];
        float4 w2a = *(const float4*)&sW2[(kc * 4 + 0) * KDIM + tc * 4];
        float4 w2b = *(const float4*)&sW2[(kc * 4 + 1) * KDIM + tc * 4];
        float4 w2c = *(const float4*)&sW2[(kc * 4 + 2) * KDIM + tc * 4];
        float4 w2d = *(const float4*)&sW2[(kc * 4 + 3) * KDIM + tc * 4];
#pragma unroll
        for (int i = 0; i < 4; ++i) {
            int r = tr * 4 + i;
            int ss = kc ^ ((r >> 2) & 7);
            float4 sv = *(const float4*)&sS[r * KDIM + ss * 4];
            float4 pv = *(const float4*)&sP[r * KDIM + ss * 4];
            acc[i][0] += sv.x * w1a.x + pv.x * w2a.x;
            acc[i][1] += sv.x * w1a.y + pv.x * w2a.y;
            acc[i][2] += sv.x * w1a.z + pv.x * w2a.z;
            acc[i][3] += sv.x * w1a.w + pv.x * w2a.w;
            acc[i][0] += sv.y * w1b.x + pv.y * w2b.x;
            acc[i][1] += sv.y * w1b.y + pv.y * w2b.y;
            acc[i][2] += sv.y * w1b.z + pv.y * w2b.z;
            acc[i][3] += sv.y * w1b.w + pv.y * w2b.w;
            acc[i][0] += sv.z * w1c.x + pv.z * w2c.x;
            acc[i][1] += sv.z * w1c.y + pv.z * w2c.y;
            acc[i][2] += sv.z * w1c.z + pv.z * w2c.z;
            acc[i][3] += sv.z * w1c.w + pv.z * w2c.w;
            acc[i][0] += sv.w * w1d.x + pv.w * w2d.x;
            acc[i][1] += sv.w * w1d.y + pv.w * w2d.y;
            acc[i][2] += sv.w * w1d.z + pv.w * w2d.z;
            acc[i][3] += sv.w * w1d.w + pv.w * w2d.w;
        }
    }

#pragma unroll
    for (int i = 0; i < 4; ++i) {
        float sq = 0.f;
#pragma unroll
        for (int j = 0; j < 4; ++j) {
            float h = acc[i][j];
            h = h > 0.f ? h : SLOPE * h;
            acc[i][j] = h;
            sq += h * h;
        }
#pragma unroll
        for (int off = 1; off < 16; off <<= 1) sq += __shfl_xor(sq, off);
        float scale = 1.0f / fmaxf(sqrtf(sq), 1e-12f);
        int node = n0 + tr * 4 + i;
        if (node < NN) {
            float4 o = make_float4(acc[i][0] * scale, acc[i][1] * scale, acc[i][2] * scale,
                                   acc[i][3] * scale);
            *(float4*)(xout + (long long)node * KDIM + tc * 4) = o;
            ushort4 h4;
            h4.x = f2bf(o.x); h4.y = f2bf(o.y); h4.z = f2bf(o.z); h4.w = f2bf(o.w);
            *(ushort4*)(xh + (long long)node * KDIM + tc * 4) = h4;
        }
    }
}

// ---------------- gather batch rows into accB (mean accumulator over layers) ----------------
__global__ __launch_bounds__(256) void gather_acc_kernel(const float* __restrict__ x,
                                                         const int* __restrict__ users,
                                                         const int* __restrict__ items,
                                                         float* __restrict__ accB, int mode) {
    int tid = blockIdx.x * blockDim.x + threadIdx.x;  // over 2*BATCH*KDIM
    if (tid >= 2 * BATCH * KDIM) return;
    int b = tid >> 6, lane = tid & 63;
    int node = (b < BATCH) ? users[b] : (NUSERS + items[b - BATCH]);
    float v = x[(long long)node * KDIM + lane];
    if (mode == 0)
        accB[tid] = v;
    else
        accB[tid] += v;
}

// ---------------- transpose proj_w [64,2048] -> wt [2048,64] ----------------
__global__ __launch_bounds__(256) void transpose_w_kernel(const float* __restrict__ pw,
                                                          float* __restrict__ wt) {
    int tid = blockIdx.x * blockDim.x + threadIdx.x;
    if (tid >= KDIM * FEAT) return;
    int j = tid / FEAT, k = tid % FEAT;
    wt[k * KDIM + j] = pw[tid];
}

// ---------------- projection: projB[b] = l2norm(F[items[b]] @ pw^T + pb) ----------------
__global__ __launch_bounds__(256) void proj_kernel(const float* __restrict__ F,
                                                   const float* __restrict__ wt,
                                                   const float* __restrict__ pb,
                                                   const int* __restrict__ items,
                                                   float* __restrict__ projB) {
    int lane = threadIdx.x & 63;
    int wid = threadIdx.x >> 6;
    int gwave = blockIdx.x * 4 + wid;
    int i0 = gwave * 4;
    if (i0 >= BATCH) return;
    const float* f0 = F + (long long)items[i0 + 0] * FEAT;
    const float* f1 = F + (long long)items[i0 + 1] * FEAT;
    const float* f2 = F + (long long)items[i0 + 2] * FEAT;
    const float* f3 = F + (long long)items[i0 + 3] * FEAT;
    float c0 = 0.f, c1 = 0.f, c2 = 0.f, c3 = 0.f;
    for (int kk = 0; kk < FEAT; kk += 64) {
        float a0 = f0[kk + lane];
        float a1 = f1[kk + lane];
        float a2 = f2[kk + lane];
        float a3 = f3[kk + lane];
#pragma unroll
        for (int k2 = 0; k2 < 64; ++k2) {
            float w = wt[(kk + k2) * KDIM + lane];
            c0 += __shfl(a0, k2) * w;
            c1 += __shfl(a1, k2) * w;
            c2 += __shfl(a2, k2) * w;
            c3 += __shfl(a3, k2) * w;
        }
    }
    float bias = pb[lane];
    c0 += bias; c1 += bias; c2 += bias; c3 += bias;
    float s0 = c0 * c0, s1 = c1 * c1, s2 = c2 * c2, s3 = c3 * c3;
#pragma unroll
    for (int off = 32; off > 0; off >>= 1) {
        s0 += __shfl_xor(s0, off);
        s1 += __shfl_xor(s1, off);
        s2 += __shfl_xor(s2, off);
        s3 += __shfl_xor(s3, off);
    }
    projB[(long long)(i0 + 0) * KDIM + lane] = c0 * (1.0f / fmaxf(sqrtf(s0), 1e-12f));
    projB[(long long)(i0 + 1) * KDIM + lane] = c1 * (1.0f / fmaxf(sqrtf(s1), 1e-12f));
    projB[(long long)(i0 + 2) * KDIM + lane] = c2 * (1.0f / fmaxf(sqrtf(s2), 1e-12f));
    projB[(long long)(i0 + 3) * KDIM + lane] = c3 * (1.0f / fmaxf(sqrtf(s3), 1e-12f));
}

// ---------------- final: xui = dot(gamma_u, gamma_i) + dot(theta_u, proj_i) ----------------
__global__ __launch_bounds__(256) void final_kernel(const float* __restrict__ accB,
                                                    const float* __restrict__ Tu,
                                                    const float* __restrict__ projB,
                                                    const int* __restrict__ users,
                                                    float* __restrict__ out) {
    int lane = threadIdx.x & 63;
    int wid = threadIdx.x >> 6;
    int b = blockIdx.x * 4 + wid;
    if (b >= BATCH) return;
    float gu = accB[(long long)b * KDIM + lane];
    float gi = accB[(long long)(BATCH + b) * KDIM + lane];
    float tu = Tu[(long long)users[b] * KDIM + lane];
    float pi = projB[(long long)b * KDIM + lane];
    float v = gu * gi * (1.0f / 16.0f) + tu * pi;  // (acc/4)·(acc/4)
#pragma unroll
    for (int off = 32; off > 0; off >>= 1) v += __shfl_xor(v, off);
    if (lane == 0) out[b] = v;
}

extern "C" void kernel_launch(void* const* d_in, const int* in_sizes, int n_in,
                              void* d_out, int out_size, void* d_ws, size_t ws_size,
                              hipStream_t stream) {
    const float* Gu = (const float*)d_in[0];
    const float* Gi = (const float*)d_in[1];
    const float* Tu = (const float*)d_in[2];
    const float* F = (const float*)d_in[3];
    const float* pw = (const float*)d_in[4];
    const float* pb = (const float*)d_in[5];
    const float* W1 = (const float*)d_in[6];
    const float* b1 = (const float*)d_in[7];
    const float* W2 = (const float*)d_in[8];
    const float* b2 = (const float*)d_in[9];
    const float* ew = (const float*)d_in[10];
    const int* ei = (const int*)d_in[11];
    const int* users = (const int*)d_in[12];
    const int* items = (const int*)d_in[13];
    float* out = (float*)d_out;

    float* xa = (float*)d_ws;                         // NN*KDIM
    float* xb = xa + (size_t)NN * KDIM;               // NN*KDIM
    float* agg = xb + (size_t)NN * KDIM;              // NN*KDIM
    float* accB = agg + (size_t)NN * KDIM;            // 2*BATCH*KDIM
    float* wt = accB + (size_t)2 * BATCH * KDIM;      // FEAT*KDIM
    float* projB = wt + (size_t)FEAT * KDIM;          // BATCH*KDIM
    int* deg = (int*)(projB + (size_t)BATCH * KDIM);  // DEG_PAD
    int* row_start = deg + DEG_PAD;                   // DEG_PAD
    int* cursor = row_start + DEG_PAD;                // DEG_PAD
    int* bsum = cursor + DEG_PAD;                     // 128
    int* boff = bsum + 128;                           // 128
    int2* csr = (int2*)(boff + 128);                  // NEDGES int2
    unsigned short* xh = (unsigned short*)(csr + NEDGES);  // NN*KDIM bf16

    // x = concat(Gu, Gi), bf16 mirror
    init_x_kernel<<<(int)(((long long)NN * KDIM / 4 + 255) / 256), 256, 0, stream>>>(Gu, Gi, xa, xh);
    gather_acc_kernel<<<(2 * BATCH * KDIM) / 256, 256, 0, stream>>>(xa, users, items, accB, 0);
    transpose_w_kernel<<<(KDIM * FEAT) / 256, 256, 0, stream>>>(pw, wt);

    // CSR build (once; graph is static across layers)
    hipMemsetAsync(deg, 0, (size_t)DEG_PAD * sizeof(int), stream);
    hist_kernel<<<(NEDGES + 255) / 256, 256, 0, stream>>>(ei, deg);
    scan_part_kernel<<<SCAN_BLOCKS, 256, 0, stream>>>(deg, bsum);
    scan_tops_kernel<<<1, 128, 0, stream>>>(bsum, boff);
    scan_final_kernel<<<SCAN_BLOCKS, 256, 0, stream>>>(deg, boff, row_start, cursor);
    fill_kernel<<<(NEDGES + 255) / 256, 256, 0, stream>>>(ei, ew, cursor, csr);

    float* xc = xa;
    float* xn = xb;
    for (int l = 0; l < NLAYERS; ++l) {
        agg_kernel<<<(NN + 15) / 16, 256, 0, stream>>>(xh, csr, row_start, agg);
        gemm_layer_kernel<<<(NN + 63) / 64, 256, 0, stream>>>(xc, agg, W1, b1, W2, b2, xn, xh, l);
        gather_acc_kernel<<<(2 * BATCH * KDIM) / 256, 256, 0, stream>>>(xn, users, items, accB, 1);
        float* tmp = xc; xc = xn; xn = tmp;
    }

    proj_kernel<<<BATCH / 16, 256, 0, stream>>>(F, wt, pb, items, projB);
    final_kernel<<<BATCH / 4, 256, 0, stream>>>(accB, Tu, projB, users, out);
}